// Round 9
// baseline (2776.648 us; speedup 1.0000x reference)
//
#include <hip/hip_runtime.h>
#include <hip/hip_bf16.h>

typedef __bf16 bf16_t;
typedef __bf16 bf16x8 __attribute__((ext_vector_type(8)));
typedef __bf16 bf16x4 __attribute__((ext_vector_type(4)));
typedef float  f32x4  __attribute__((ext_vector_type(4)));
typedef unsigned int u32;
typedef unsigned long long u64;

#define HID 512
#define BATCH 256
#define TIN 168
#define TOUT 48
#define FEAT 128
#define NSTEPS (TIN + TOUT)   // 216
#define NGRP 8                // batch groups
#define NJT 32                // blocks per group (j-tiles of 16)
#define GRPB 32               // batch rows per group

__device__ __forceinline__ float sigmoidf_(float x) {
    x = fminf(fmaxf(x, -30.f), 30.f);
    return 1.f / (1.f + __expf(-x));
}
__device__ __forceinline__ float tanhf_(float x) {
    x = fminf(fmaxf(x, -15.f), 15.f);
    float e = __expf(2.f * x);
    return (e - 1.f) / (e + 1.f);
}

// ---------------------------------------------------------------------------
// h exchange: u32 words = (epoch << 16) | bf16_bits, through IC via
// system-scope RELAXED atomics (sc0 sc1 — R4-proven semantics, no cache
// maintenance). The epoch tag makes data self-synchronizing: no flags,
// no producer drain, ONE IC round-trip per step on the critical path.

// Poll NF fragments (8 u32 each, frag stride 32 cols) until every word
// carries `epoch`, then pack to bf16x8. All indices compile-time (rule #20).
template <int NF>
__device__ __forceinline__ void poll_h(const u32* __restrict__ baseLane,
                                       unsigned int epoch, bf16x8* out) {
    u32 w[NF][8];
    for (;;) {
        #pragma unroll
        for (int f = 0; f < NF; ++f)
            #pragma unroll
            for (int j = 0; j < 8; ++j)
                w[f][j] = __hip_atomic_load(baseLane + f * 32 + j,
                                            __ATOMIC_RELAXED, __HIP_MEMORY_SCOPE_SYSTEM);
        bool ok = true;
        #pragma unroll
        for (int f = 0; f < NF; ++f)
            #pragma unroll
            for (int j = 0; j < 8; ++j)
                ok = ok && ((w[f][j] >> 16) == epoch);
        if (__all((int)ok)) break;
        __builtin_amdgcn_s_sleep(1);
    }
    #pragma unroll
    for (int f = 0; f < NF; ++f) {
        union { u32 u[4]; bf16x8 v; } pk;
        pk.u[0] = (w[f][0] & 0xffffu) | (w[f][1] << 16);
        pk.u[1] = (w[f][2] & 0xffffu) | (w[f][3] << 16);
        pk.u[2] = (w[f][4] & 0xffffu) | (w[f][5] << 16);
        pk.u[3] = (w[f][6] & 0xffffu) | (w[f][7] << 16);
        out[f] = pk.v;
    }
}

__device__ __forceinline__ void st_h32(u32* p, float v, unsigned int epoch) {
    bf16_t b = (bf16_t)v;
    unsigned short us;
    __builtin_memcpy(&us, &b, 2);
    u32 w = (epoch << 16) | (u32)us;
    __hip_atomic_store(p, w, __ATOMIC_RELAXED, __HIP_MEMORY_SCOPE_SYSTEM);
}

// ---------------------------------------------------------------------------
// Cast x (B,T,F) fp32 -> Xbf (T,B,F) bf16
__global__ __launch_bounds__(256)
void cast_x_kernel(const float* __restrict__ x, bf16_t* __restrict__ Xbf) {
    int q = blockIdx.x * 256 + threadIdx.x;
    if (q >= BATCH * TIN * (FEAT / 4)) return;
    int f4  = q & 31;
    int rem = q >> 5;
    int t = rem % TIN;
    int b = rem / TIN;
    float4 v = *(const float4*)&x[((size_t)b * TIN + t) * FEAT + f4 * 4];
    bf16x4 o = { (bf16_t)v.x, (bf16_t)v.y, (bf16_t)v.z, (bf16_t)v.w };
    *(bf16x4*)&Xbf[((size_t)t * BATCH + b) * FEAT + f4 * 4] = o;
}

// Build Wcat (2048 x 640) bf16 = [Wih | Whh]
__global__ __launch_bounds__(256)
void cast_wcat_kernel(const float* __restrict__ Wih, const float* __restrict__ Whh,
                      bf16_t* __restrict__ Wcat) {
    int q = blockIdx.x * 256 + threadIdx.x;
    int k4 = q % 160;
    int r  = q / 160;
    if (r >= 2048) return;
    int k = k4 * 4;
    float4 v;
    if (k < FEAT) v = *(const float4*)&Wih[(size_t)r * FEAT + k];
    else          v = *(const float4*)&Whh[(size_t)r * HID + (k - FEAT)];
    bf16x4 o = { (bf16_t)v.x, (bf16_t)v.y, (bf16_t)v.z, (bf16_t)v.w };
    *(bf16x4*)&Wcat[(size_t)r * 640 + k] = o;
}

// Cast W_lin (128 x 512) fp32 -> bf16
__global__ __launch_bounds__(256)
void cast_wlin_kernel(const float* __restrict__ W, bf16_t* __restrict__ Wb) {
    int q = blockIdx.x * 256 + threadIdx.x;
    if (q >= FEAT * HID / 4) return;
    float4 v = *(const float4*)&W[q * 4];
    bf16x4 o = { (bf16_t)v.x, (bf16_t)v.y, (bf16_t)v.z, (bf16_t)v.w };
    *(bf16x4*)&Wb[q * 4] = o;
}

// Wcomb (2048 x 512) = dec_Wih (2048x128) @ W_lin (128x512) + dec_Whh, bf16 out
__global__ __launch_bounds__(256)
void build_wcomb_kernel(const float* __restrict__ dWih, const float* __restrict__ dWhh,
                        const float* __restrict__ Wlin, bf16_t* __restrict__ Wcomb) {
    __shared__ float As[64][128];
    __shared__ float Bs[128][64];
    int r0 = blockIdx.x * 64, c0 = blockIdx.y * 64;
    int tid = threadIdx.x;
    for (int i = tid; i < 64 * 32; i += 256) {
        int rr = i >> 5, cc = (i & 31) << 2;
        *(float4*)&As[rr][cc] = *(const float4*)&dWih[(size_t)(r0 + rr) * 128 + cc];
    }
    for (int i = tid; i < 128 * 16; i += 256) {
        int kk = i >> 4, cc = (i & 15) << 2;
        *(float4*)&Bs[kk][cc] = *(const float4*)&Wlin[(size_t)kk * HID + c0 + cc];
    }
    __syncthreads();
    int tx = tid & 15, ty = tid >> 4;
    float acc[4][4] = {};
    for (int k = 0; k < 128; ++k) {
        float a[4], b[4];
        #pragma unroll
        for (int i = 0; i < 4; ++i) a[i] = As[ty * 4 + i][k];
        #pragma unroll
        for (int j = 0; j < 4; ++j) b[j] = Bs[k][tx * 4 + j];
        #pragma unroll
        for (int i = 0; i < 4; ++i)
            #pragma unroll
            for (int j = 0; j < 4; ++j) acc[i][j] += a[i] * b[j];
    }
    for (int i = 0; i < 4; ++i) {
        int r = r0 + ty * 4 + i;
        for (int j = 0; j < 4; ++j) {
            int cc = c0 + tx * 4 + j;
            Wcomb[(size_t)r * HID + cc] = (bf16_t)(acc[i][j] + dWhh[(size_t)r * HID + cc]);
        }
    }
}

// ---------------------------------------------------------------------------
// Persistent seq2seq LSTM. 256 blocks x 256 threads (R4 skeleton).
// Block -> (group g = bid&7, j-tile jt = bid>>3). Group owns 32 batch rows;
// block owns 16 hidden cols. Waves: bh = wave&1, gp = wave>>1 (K half).
// Weights pinned in regs; c register-resident.
// Step: poll own h words (epoch-tagged) -> MFMA -> gp1 writes Ex -> barrier
// -> gp0 merges + cell + stores tagged h (NO drain, NO flag) -> barrier.
//
// Ping-pong overwrite safety: step t+1 producers (writing hbuf[t&1], epoch
// t+2) causally follow every block's step-t+1 poll success, which follows
// every block's step-t production, which follows that block's step-t
// consumption of hbuf[t&1]. So no consumer can still be reading epoch-t data
// when it is overwritten.

// gp0-wave epilogue: merge K-halves, cell update, store tagged h
__device__ __forceinline__ void cell_store(
    f32x4 (&acc)[4], float (&cacc)[4], const float (*Exp)[GRPB][17],
    int bh, int l4, int l15, int b0, int jcol, unsigned int epoch_next,
    u32* __restrict__ hnext)
{
    #pragma unroll
    for (int q = 0; q < 4; ++q)
        #pragma unroll
        for (int r = 0; r < 4; ++r)
            acc[q][r] += Exp[q][bh * 16 + l4 * 4 + r][l15];
    #pragma unroll
    for (int r = 0; r < 4; ++r) {
        float cn = sigmoidf_(acc[1][r]) * cacc[r] + sigmoidf_(acc[0][r]) * tanhf_(acc[2][r]);
        cacc[r] = cn;
        float hv = sigmoidf_(acc[3][r]) * tanhf_(cn);
        int row = b0 + l4 * 4 + r;
        st_h32(hnext + (size_t)row * HID + jcol, hv, epoch_next);
    }
}

__global__ __launch_bounds__(256, 1)
void lstm_persist(const bf16_t* __restrict__ Xbf,
                  const bf16_t* __restrict__ Wenc, const float* __restrict__ enc_b,
                  const bf16_t* __restrict__ Wdec1, const bf16_t* __restrict__ Wcomb,
                  const float* __restrict__ dec_b,
                  u32* __restrict__ h32A, u32* __restrict__ h32B,
                  u32* __restrict__ Hdec32)
{
    __shared__ float Ex[4][GRPB][17];
    const int bid = blockIdx.x;
    const int g   = bid & (NGRP - 1);
    const int jt  = bid >> 3;
    const int j0  = jt * 16;
    const int tid = threadIdx.x;
    const int wave = tid >> 6, lane = tid & 63;
    const int l15 = lane & 15, l4 = lane >> 4;
    const int bh = wave & 1, gp = wave >> 1;
    const int b0 = g * GRPB + bh * 16;
    const int arow = b0 + l15;   // A-operand (batch) row this lane loads
    const int jcol = j0 + l15;   // output hidden column

    float biasE[4], biasD[4];
    #pragma unroll
    for (int q = 0; q < 4; ++q) {
        biasE[q] = enc_b[q * HID + jcol];
        biasD[q] = dec_b[q * HID + jcol];
    }
    float cacc[4] = {0.f, 0.f, 0.f, 0.f};

    bf16x8 Breg[40];
    const int kc0 = gp * 320;    // K-half base for K=640 phases

    // ---- encoder weight fragments (K=640), pinned
    #pragma unroll
    for (int q = 0; q < 4; ++q)
        #pragma unroll
        for (int i = 0; i < 10; ++i)
            Breg[q * 10 + i] = *(const bf16x8*)(
                Wenc + (size_t)(q * HID + jcol) * 640 + kc0 + i * 32 + l4 * 8);
    #pragma unroll
    for (int n = 0; n < 40; ++n) asm volatile("" : "+v"(Breg[n]));

    // ================= encoder: t = 0..167 =================
    for (int t = 0; t < TIN; ++t) {
        const u32* hb32 = (t & 1) ? h32B : h32A;
        u32* hn32       = (t & 1) ? h32A : h32B;
        bf16x8 a[10];
        if (gp == 0) {
            const bf16_t* xb = Xbf + ((size_t)t * BATCH + arow) * FEAT + l4 * 8;
            #pragma unroll
            for (int i = 0; i < 4; ++i) a[i] = *(const bf16x8*)(xb + i * 32);
            // h cols 0..192 (K 128..320), expect epoch t
            poll_h<6>(hb32 + (size_t)arow * HID + l4 * 8, (unsigned)t, &a[4]);
        } else {
            // h cols 192..512 (K 320..640)
            poll_h<10>(hb32 + (size_t)arow * HID + 192 + l4 * 8, (unsigned)t, &a[0]);
        }
        f32x4 acc[4];
        #pragma unroll
        for (int q = 0; q < 4; ++q) {
            float bv = (gp == 0) ? biasE[q] : 0.f;
            acc[q] = (f32x4){bv, bv, bv, bv};
        }
        #pragma unroll
        for (int i = 0; i < 10; ++i)
            #pragma unroll
            for (int q = 0; q < 4; ++q)
                acc[q] = __builtin_amdgcn_mfma_f32_16x16x32_bf16(a[i], Breg[q * 10 + i], acc[q], 0, 0, 0);
        if (gp == 1) {
            #pragma unroll
            for (int q = 0; q < 4; ++q)
                #pragma unroll
                for (int r = 0; r < 4; ++r)
                    Ex[q][bh * 16 + l4 * 4 + r][l15] = acc[q][r];
        }
        __syncthreads();
        if (gp == 0)
            cell_store(acc, cacc, Ex, bh, l4, l15, b0, jcol, (unsigned)(t + 1), hn32);
        __syncthreads();
    }

    // ---- decoder step 0 weights (Wdec1, K=640)
    #pragma unroll
    for (int q = 0; q < 4; ++q)
        #pragma unroll
        for (int i = 0; i < 10; ++i)
            Breg[q * 10 + i] = *(const bf16x8*)(
                Wdec1 + (size_t)(q * HID + jcol) * 640 + kc0 + i * 32 + l4 * 8);
    #pragma unroll
    for (int n = 0; n < 40; ++n) asm volatile("" : "+v"(Breg[n]));

    // ================= decoder step 0: t = 168 =================
    {
        const int t = TIN;   // h_168 in h32A (written at t=167), epoch 168
        bf16x8 a[10];
        if (gp == 0) {
            const bf16_t* xb = Xbf + ((size_t)(TIN - 1) * BATCH + arow) * FEAT + l4 * 8;
            #pragma unroll
            for (int i = 0; i < 4; ++i) a[i] = *(const bf16x8*)(xb + i * 32);
            poll_h<6>(h32A + (size_t)arow * HID + l4 * 8, (unsigned)t, &a[4]);
        } else {
            poll_h<10>(h32A + (size_t)arow * HID + 192 + l4 * 8, (unsigned)t, &a[0]);
        }
        f32x4 acc[4];
        #pragma unroll
        for (int q = 0; q < 4; ++q) {
            float bv = (gp == 0) ? biasD[q] : 0.f;
            acc[q] = (f32x4){bv, bv, bv, bv};
        }
        #pragma unroll
        for (int i = 0; i < 10; ++i)
            #pragma unroll
            for (int q = 0; q < 4; ++q)
                acc[q] = __builtin_amdgcn_mfma_f32_16x16x32_bf16(a[i], Breg[q * 10 + i], acc[q], 0, 0, 0);
        if (gp == 1) {
            #pragma unroll
            for (int q = 0; q < 4; ++q)
                #pragma unroll
                for (int r = 0; r < 4; ++r)
                    Ex[q][bh * 16 + l4 * 4 + r][l15] = acc[q][r];
        }
        __syncthreads();
        if (gp == 0)
            cell_store(acc, cacc, Ex, bh, l4, l15, b0, jcol, (unsigned)(t + 1), Hdec32);
        __syncthreads();
    }

    // ---- folded decoder weights (Wcomb, K=512)
    const int kd0 = gp * 256;
    #pragma unroll
    for (int q = 0; q < 4; ++q)
        #pragma unroll
        for (int i = 0; i < 8; ++i)
            Breg[q * 8 + i] = *(const bf16x8*)(
                Wcomb + (size_t)(q * HID + jcol) * HID + kd0 + i * 32 + l4 * 8);
    #pragma unroll
    for (int n = 0; n < 32; ++n) asm volatile("" : "+v"(Breg[n]));

    // ================= decoder: t = 169..215 =================
    for (int t = TIN + 1; t < NSTEPS; ++t) {
        const u32* hprev32 = Hdec32 + (size_t)(t - 1 - TIN) * BATCH * HID;
        bf16x8 a[8];
        poll_h<8>(hprev32 + (size_t)arow * HID + kd0 + l4 * 8, (unsigned)t, &a[0]);
        f32x4 acc[4];
        #pragma unroll
        for (int q = 0; q < 4; ++q) {
            float bv = (gp == 0) ? biasD[q] : 0.f;
            acc[q] = (f32x4){bv, bv, bv, bv};
        }
        #pragma unroll
        for (int i = 0; i < 8; ++i)
            #pragma unroll
            for (int q = 0; q < 4; ++q)
                acc[q] = __builtin_amdgcn_mfma_f32_16x16x32_bf16(a[i], Breg[q * 8 + i], acc[q], 0, 0, 0);
        if (gp == 1) {
            #pragma unroll
            for (int q = 0; q < 4; ++q)
                #pragma unroll
                for (int r = 0; r < 4; ++r)
                    Ex[q][bh * 16 + l4 * 4 + r][l15] = acc[q][r];
        }
        __syncthreads();
        if (gp == 0)
            cell_store(acc, cacc, Ex, bh, l4, l15, b0, jcol, (unsigned)(t + 1),
                       Hdec32 + (size_t)(t - TIN) * BATCH * HID);
        __syncthreads();
    }
}

// ---------------------------------------------------------------------------
// Final projection: out[b,t,f] = sum_j h(Hdec32[t][b][j]) * Wlin[f][j]
__global__ __launch_bounds__(128)
void final_proj_kernel(const u32* __restrict__ Hdec32, const bf16_t* __restrict__ Wlin,
                       float* __restrict__ out) {
    int tid = threadIdx.x;
    int wv = tid >> 6, lane = tid & 63;
    int l15 = lane & 15, l4 = lane >> 4;
    int row0 = blockIdx.x * 32 + wv * 16;
    const u32* arow = Hdec32 + (size_t)(row0 + l15) * HID;
    f32x4 acc[8];
    #pragma unroll
    for (int n = 0; n < 8; ++n) acc[n] = (f32x4){0.f, 0.f, 0.f, 0.f};
    for (int kc = 0; kc < HID; kc += 32) {
        u32 w[8];
        #pragma unroll
        for (int j = 0; j < 8; ++j) w[j] = arow[kc + l4 * 8 + j];
        union { u32 u[4]; bf16x8 v; } pk;
        pk.u[0] = (w[0] & 0xffffu) | (w[1] << 16);
        pk.u[1] = (w[2] & 0xffffu) | (w[3] << 16);
        pk.u[2] = (w[4] & 0xffffu) | (w[5] << 16);
        pk.u[3] = (w[6] & 0xffffu) | (w[7] << 16);
        bf16x8 af = pk.v;
        #pragma unroll
        for (int n = 0; n < 8; ++n) {
            bf16x8 bfr = *(const bf16x8*)(Wlin + (size_t)(n * 16 + l15) * HID + kc + l4 * 8);
            acc[n] = __builtin_amdgcn_mfma_f32_16x16x32_bf16(af, bfr, acc[n], 0, 0, 0);
        }
    }
    #pragma unroll
    for (int n = 0; n < 8; ++n) {
        int f = n * 16 + l15;
        #pragma unroll
        for (int r = 0; r < 4; ++r) {
            int row = row0 + l4 * 4 + r;
            int t = row >> 8;
            int b = row & 255;
            out[(size_t)b * (TOUT * FEAT) + (size_t)t * FEAT + f] = acc[n][r];
        }
    }
}

// ---------------------------------------------------------------------------
extern "C" void kernel_launch(void* const* d_in, const int* in_sizes, int n_in,
                              void* d_out, int out_size, void* d_ws, size_t ws_size,
                              hipStream_t stream) {
    const float* x       = (const float*)d_in[0];
    const float* enc_Wih = (const float*)d_in[1];
    const float* enc_Whh = (const float*)d_in[2];
    const float* enc_b   = (const float*)d_in[3];
    const float* dec_Wih = (const float*)d_in[4];
    const float* dec_Whh = (const float*)d_in[5];
    const float* dec_b   = (const float*)d_in[6];
    const float* W_lin   = (const float*)d_in[7];
    float* out = (float*)d_out;

    char* p = (char*)d_ws;
    auto alloc = [&](size_t bytes) -> void* {
        void* r = (void*)p;
        p += (bytes + 255) & ~(size_t)255;
        return r;
    };
    bf16_t* Xbf    = (bf16_t*)alloc((size_t)TIN * BATCH * FEAT * 2);   // 11 MB
    bf16_t* Wenc   = (bf16_t*)alloc((size_t)2048 * 640 * 2);           // 2.6 MB
    bf16_t* Wdec1  = (bf16_t*)alloc((size_t)2048 * 640 * 2);           // 2.6 MB
    bf16_t* Wcomb  = (bf16_t*)alloc((size_t)2048 * HID * 2);           // 2.1 MB
    bf16_t* Wlinb  = (bf16_t*)alloc((size_t)FEAT * HID * 2);           // 128 KB
    u32*    h32A   = (u32*)alloc((size_t)BATCH * HID * 4);             // 512 KB
    u32*    h32B   = (u32*)alloc((size_t)BATCH * HID * 4);             // 512 KB
    u32*    Hdec32 = (u32*)alloc((size_t)TOUT * BATCH * HID * 4);      // 25 MB

    // per-launch state init (replay-safe; epoch-exact match needs clean tags)
    (void)hipMemsetAsync(h32A,   0, (size_t)BATCH * HID * 4, stream);
    (void)hipMemsetAsync(h32B,   0, (size_t)BATCH * HID * 4, stream);
    (void)hipMemsetAsync(Hdec32, 0, (size_t)TOUT * BATCH * HID * 4, stream);

    // precompute
    cast_x_kernel<<<(BATCH * TIN * (FEAT / 4) + 255) / 256, 256, 0, stream>>>(x, Xbf);
    cast_wcat_kernel<<<(2048 * 160 + 255) / 256, 256, 0, stream>>>(enc_Wih, enc_Whh, Wenc);
    cast_wcat_kernel<<<(2048 * 160 + 255) / 256, 256, 0, stream>>>(dec_Wih, dec_Whh, Wdec1);
    cast_wlin_kernel<<<(FEAT * HID / 4 + 255) / 256, 256, 0, stream>>>(W_lin, Wlinb);
    build_wcomb_kernel<<<dim3(2048 / 64, HID / 64), 256, 0, stream>>>(dec_Wih, dec_Whh, W_lin, Wcomb);

    // all 216 recurrent steps in one persistent kernel
    lstm_persist<<<NGRP * NJT, 256, 0, stream>>>(Xbf, Wenc, enc_b, Wdec1, Wcomb, dec_b,
                                                 h32A, h32B, Hdec32);

    // batched output projection (48 x 256 rows @ W_lin^T)
    final_proj_kernel<<<(TOUT * BATCH) / 32, 128, 0, stream>>>(Hdec32, Wlinb, out);
}

// Round 10
// 1003.294 us; speedup vs baseline: 2.7675x; 2.7675x over previous
//
#include <hip/hip_runtime.h>
#include <hip/hip_bf16.h>

typedef __bf16 bf16_t;
typedef __bf16 bf16x8 __attribute__((ext_vector_type(8)));
typedef __bf16 bf16x4 __attribute__((ext_vector_type(4)));
typedef float  f32x4  __attribute__((ext_vector_type(4)));
typedef unsigned int u32;
typedef unsigned long long u64;

#define HID 512
#define BATCH 256
#define TIN 168
#define TOUT 48
#define FEAT 128
#define NSTEPS (TIN + TOUT)   // 216
#define NGRP 8                // batch groups
#define NJT 32                // blocks per group (j-tiles of 16)
#define GRPB 32               // batch rows per group

__device__ __forceinline__ float sigmoidf_(float x) {
    x = fminf(fmaxf(x, -30.f), 30.f);
    return 1.f / (1.f + __expf(-x));
}
__device__ __forceinline__ float tanhf_(float x) {
    x = fminf(fmaxf(x, -15.f), 15.f);
    float e = __expf(2.f * x);
    return (e - 1.f) / (e + 1.f);
}

// Coherent IC-through primitives (R4-proven): RELAXED system-scope atomics
// compile to global_load/store ... sc0 sc1 — no cache-maintenance ops.
__device__ __forceinline__ bf16x8 ld_h8(const bf16_t* p) {
    union { u64 q[2]; bf16x8 v; } u;
    u.q[0] = __hip_atomic_load((const u64*)p,     __ATOMIC_RELAXED,
                               __HIP_MEMORY_SCOPE_SYSTEM);
    u.q[1] = __hip_atomic_load((const u64*)p + 1, __ATOMIC_RELAXED,
                               __HIP_MEMORY_SCOPE_SYSTEM);
    return u.v;
}
// one 8B store of 4 consecutive bf16 h-values (R5-proven u64 atomic store)
__device__ __forceinline__ void st_h4(bf16_t* p, float v0, float v1, float v2, float v3) {
    bf16_t b0 = (bf16_t)v0, b1 = (bf16_t)v1, b2 = (bf16_t)v2, b3 = (bf16_t)v3;
    unsigned short s0, s1, s2, s3;
    __builtin_memcpy(&s0, &b0, 2); __builtin_memcpy(&s1, &b1, 2);
    __builtin_memcpy(&s2, &b2, 2); __builtin_memcpy(&s3, &b3, 2);
    u64 w = (u64)s0 | ((u64)s1 << 16) | ((u64)s2 << 32) | ((u64)s3 << 48);
    __hip_atomic_store((u64*)p, w, __ATOMIC_RELAXED, __HIP_MEMORY_SCOPE_SYSTEM);
}

// ---------------------------------------------------------------------------
// Cast x (B,T,F) fp32 -> Xbf (T,B,F) bf16
__global__ __launch_bounds__(256)
void cast_x_kernel(const float* __restrict__ x, bf16_t* __restrict__ Xbf) {
    int q = blockIdx.x * 256 + threadIdx.x;
    if (q >= BATCH * TIN * (FEAT / 4)) return;
    int f4  = q & 31;
    int rem = q >> 5;
    int t = rem % TIN;
    int b = rem / TIN;
    float4 v = *(const float4*)&x[((size_t)b * TIN + t) * FEAT + f4 * 4];
    bf16x4 o = { (bf16_t)v.x, (bf16_t)v.y, (bf16_t)v.z, (bf16_t)v.w };
    *(bf16x4*)&Xbf[((size_t)t * BATCH + b) * FEAT + f4 * 4] = o;
}

// Build Wcat (2048 x 640) bf16 = [Wih | Whh]
__global__ __launch_bounds__(256)
void cast_wcat_kernel(const float* __restrict__ Wih, const float* __restrict__ Whh,
                      bf16_t* __restrict__ Wcat) {
    int q = blockIdx.x * 256 + threadIdx.x;
    int k4 = q % 160;
    int r  = q / 160;
    if (r >= 2048) return;
    int k = k4 * 4;
    float4 v;
    if (k < FEAT) v = *(const float4*)&Wih[(size_t)r * FEAT + k];
    else          v = *(const float4*)&Whh[(size_t)r * HID + (k - FEAT)];
    bf16x4 o = { (bf16_t)v.x, (bf16_t)v.y, (bf16_t)v.z, (bf16_t)v.w };
    *(bf16x4*)&Wcat[(size_t)r * 640 + k] = o;
}

// Cast W_lin (128 x 512) fp32 -> bf16
__global__ __launch_bounds__(256)
void cast_wlin_kernel(const float* __restrict__ W, bf16_t* __restrict__ Wb) {
    int q = blockIdx.x * 256 + threadIdx.x;
    if (q >= FEAT * HID / 4) return;
    float4 v = *(const float4*)&W[q * 4];
    bf16x4 o = { (bf16_t)v.x, (bf16_t)v.y, (bf16_t)v.z, (bf16_t)v.w };
    *(bf16x4*)&Wb[q * 4] = o;
}

// Wcomb (2048 x 512) = dec_Wih (2048x128) @ W_lin (128x512) + dec_Whh, bf16 out
__global__ __launch_bounds__(256)
void build_wcomb_kernel(const float* __restrict__ dWih, const float* __restrict__ dWhh,
                        const float* __restrict__ Wlin, bf16_t* __restrict__ Wcomb) {
    __shared__ float As[64][128];
    __shared__ float Bs[128][64];
    int r0 = blockIdx.x * 64, c0 = blockIdx.y * 64;
    int tid = threadIdx.x;
    for (int i = tid; i < 64 * 32; i += 256) {
        int rr = i >> 5, cc = (i & 31) << 2;
        *(float4*)&As[rr][cc] = *(const float4*)&dWih[(size_t)(r0 + rr) * 128 + cc];
    }
    for (int i = tid; i < 128 * 16; i += 256) {
        int kk = i >> 4, cc = (i & 15) << 2;
        *(float4*)&Bs[kk][cc] = *(const float4*)&Wlin[(size_t)kk * HID + c0 + cc];
    }
    __syncthreads();
    int tx = tid & 15, ty = tid >> 4;
    float acc[4][4] = {};
    for (int k = 0; k < 128; ++k) {
        float a[4], b[4];
        #pragma unroll
        for (int i = 0; i < 4; ++i) a[i] = As[ty * 4 + i][k];
        #pragma unroll
        for (int j = 0; j < 4; ++j) b[j] = Bs[k][tx * 4 + j];
        #pragma unroll
        for (int i = 0; i < 4; ++i)
            #pragma unroll
            for (int j = 0; j < 4; ++j) acc[i][j] += a[i] * b[j];
    }
    for (int i = 0; i < 4; ++i) {
        int r = r0 + ty * 4 + i;
        for (int j = 0; j < 4; ++j) {
            int cc = c0 + tx * 4 + j;
            Wcomb[(size_t)r * HID + cc] = (bf16_t)(acc[i][j] + dWhh[(size_t)r * HID + cc]);
        }
    }
}

// ---------------------------------------------------------------------------
// Persistent seq2seq LSTM — R4 skeleton, operand-swapped MFMA.
// 256 blocks x 256 threads. Block -> (group g = bid&7, j-tile jt = bid>>3).
// Group owns 32 batch rows; block owns 16 hidden cols. Waves: bh = wave&1
// (batch half), gp = wave>>1 (K half). Weights pinned in regs; c register-
// resident. mfma(W_frag, xh_frag, acc): D col (lane&15) = batch row,
// D row (l4*4+r) = hidden col -> each lane holds 4 CONSECUTIVE hidden cols
// for one batch row -> h write-back is ONE 8B store per lane.

// wait until all 32 blocks of group g have flag >= epoch (R4-proven)
__device__ __forceinline__ void group_wait(const u32* flags, int g, int tid,
                                           unsigned int epoch) {
    if (tid < NJT) {
        while (__hip_atomic_load(&flags[g * NJT + tid], __ATOMIC_RELAXED,
                                 __HIP_MEMORY_SCOPE_SYSTEM) < epoch)
            __builtin_amdgcn_s_sleep(1);
    }
    __syncthreads();
}

__device__ __forceinline__ void group_arrive(u32* flags, int g, int jt, int tid,
                                             unsigned int epoch) {
    if (tid == 0)
        __hip_atomic_store(&flags[g * NJT + jt], epoch, __ATOMIC_RELAXED,
                           __HIP_MEMORY_SCOPE_SYSTEM);
}

// gp1 -> Ex; barrier; gp0: merge K-halves, cell update, packed 8B h store,
// drain; barrier. (two-barrier R4 structure)
__device__ __forceinline__ void cell_finish(
    f32x4 (&acc)[4], float (&cacc)[4], f32x4 (*Ex)[2][64],
    int gp, int bh, int lane, int l15, int l4, int brow, int jq0,
    bf16_t* __restrict__ hnext)
{
    if (gp == 1) {
        #pragma unroll
        for (int q = 0; q < 4; ++q)
            Ex[q][bh][lane] = acc[q];
    }
    __syncthreads();
    if (gp == 0) {
        #pragma unroll
        for (int q = 0; q < 4; ++q)
            acc[q] += Ex[q][bh][lane];
        float hv[4];
        #pragma unroll
        for (int r = 0; r < 4; ++r) {
            float cn = sigmoidf_(acc[1][r]) * cacc[r] + sigmoidf_(acc[0][r]) * tanhf_(acc[2][r]);
            cacc[r] = cn;
            hv[r] = sigmoidf_(acc[3][r]) * tanhf_(cn);
        }
        st_h4(hnext + (size_t)brow * HID + jq0, hv[0], hv[1], hv[2], hv[3]);
        asm volatile("s_waitcnt vmcnt(0)" ::: "memory");   // h acked at IC
    }
    __syncthreads();
}

__global__ __launch_bounds__(256, 1)
void lstm_persist(const bf16_t* __restrict__ Xbf,
                  const bf16_t* __restrict__ Wenc, const float* __restrict__ enc_b,
                  const bf16_t* __restrict__ Wdec1, const bf16_t* __restrict__ Wcomb,
                  const float* __restrict__ dec_b,
                  bf16_t* __restrict__ hbufA, bf16_t* __restrict__ hbufB,
                  bf16_t* __restrict__ Hdec, u32* __restrict__ flags)
{
    __shared__ f32x4 Ex[4][2][64];     // 8 KB exchange
    const int bid = blockIdx.x;
    const int g   = bid & (NGRP - 1);
    const int jt  = bid >> 3;
    const int j0  = jt * 16;
    const int tid = threadIdx.x;
    const int wave = tid >> 6, lane = tid & 63;
    const int l15 = lane & 15, l4 = lane >> 4;
    const int bh = wave & 1, gp = wave >> 1;
    const int b0 = g * GRPB + bh * 16;
    const int arow = b0 + l15;          // batch row this lane loads/owns (B-op)
    const int jcol = j0 + l15;          // W row for fragment load (A-op)
    const int jq0  = j0 + l4 * 4;       // first of this lane's 4 hidden cols

    // bias as float4 over the lane's 4 consecutive hidden cols, per gate
    f32x4 biasE4[4], biasD4[4];
    #pragma unroll
    for (int q = 0; q < 4; ++q) {
        biasE4[q] = *(const f32x4*)&enc_b[q * HID + jq0];
        biasD4[q] = *(const f32x4*)&dec_b[q * HID + jq0];
    }
    float cacc[4] = {0.f, 0.f, 0.f, 0.f};

    bf16x8 Breg[40];
    const int kc0 = gp * 320;    // K-half base for K=640 phases

    // ---- encoder weight fragments (K=640), pinned
    #pragma unroll
    for (int q = 0; q < 4; ++q)
        #pragma unroll
        for (int i = 0; i < 10; ++i)
            Breg[q * 10 + i] = *(const bf16x8*)(
                Wenc + (size_t)(q * HID + jcol) * 640 + kc0 + i * 32 + l4 * 8);
    #pragma unroll
    for (int n = 0; n < 40; ++n) asm volatile("" : "+v"(Breg[n]));

    // ================= encoder: t = 0..167 =================
    for (int t = 0; t < TIN; ++t) {
        if (t > 0) group_wait(flags, g, tid, (unsigned)t);
        const bf16_t* hb = (t & 1) ? hbufB : hbufA;
        bf16_t* hn       = (t & 1) ? hbufA : hbufB;
        const bf16_t* xb  = Xbf + ((size_t)t * BATCH + arow) * FEAT + l4 * 8;
        const bf16_t* hbp = hb + (size_t)arow * HID + l4 * 8;
        bf16x8 a[10];
        if (gp == 0) {
            #pragma unroll
            for (int i = 0; i < 4; ++i)  a[i] = *(const bf16x8*)(xb + i * 32);
            #pragma unroll
            for (int i = 4; i < 10; ++i) a[i] = ld_h8(hbp + (i * 32 - FEAT));
        } else {
            #pragma unroll
            for (int i = 0; i < 10; ++i) a[i] = ld_h8(hbp + (320 - FEAT) + i * 32);
        }
        f32x4 acc[4];
        #pragma unroll
        for (int q = 0; q < 4; ++q)
            acc[q] = (gp == 0) ? biasE4[q] : (f32x4){0.f, 0.f, 0.f, 0.f};
        #pragma unroll
        for (int i = 0; i < 10; ++i)
            #pragma unroll
            for (int q = 0; q < 4; ++q)
                acc[q] = __builtin_amdgcn_mfma_f32_16x16x32_bf16(Breg[q * 10 + i], a[i], acc[q], 0, 0, 0);
        cell_finish(acc, cacc, Ex, gp, bh, lane, l15, l4, arow, jq0, hn);
        group_arrive(flags, g, jt, tid, (unsigned)(t + 1));
    }

    // ---- decoder step 0 weights (Wdec1, K=640)
    #pragma unroll
    for (int q = 0; q < 4; ++q)
        #pragma unroll
        for (int i = 0; i < 10; ++i)
            Breg[q * 10 + i] = *(const bf16x8*)(
                Wdec1 + (size_t)(q * HID + jcol) * 640 + kc0 + i * 32 + l4 * 8);
    #pragma unroll
    for (int n = 0; n < 40; ++n) asm volatile("" : "+v"(Breg[n]));

    // ================= decoder step 0: t = 168 =================
    {
        const int t = TIN;
        group_wait(flags, g, tid, (unsigned)t);
        // h_168 lives in hbufA (written at t=167)
        const bf16_t* xb  = Xbf + ((size_t)(TIN - 1) * BATCH + arow) * FEAT + l4 * 8;
        const bf16_t* hbp = hbufA + (size_t)arow * HID + l4 * 8;
        bf16x8 a[10];
        if (gp == 0) {
            #pragma unroll
            for (int i = 0; i < 4; ++i)  a[i] = *(const bf16x8*)(xb + i * 32);
            #pragma unroll
            for (int i = 4; i < 10; ++i) a[i] = ld_h8(hbp + (i * 32 - FEAT));
        } else {
            #pragma unroll
            for (int i = 0; i < 10; ++i) a[i] = ld_h8(hbp + (320 - FEAT) + i * 32);
        }
        f32x4 acc[4];
        #pragma unroll
        for (int q = 0; q < 4; ++q)
            acc[q] = (gp == 0) ? biasD4[q] : (f32x4){0.f, 0.f, 0.f, 0.f};
        #pragma unroll
        for (int i = 0; i < 10; ++i)
            #pragma unroll
            for (int q = 0; q < 4; ++q)
                acc[q] = __builtin_amdgcn_mfma_f32_16x16x32_bf16(Breg[q * 10 + i], a[i], acc[q], 0, 0, 0);
        cell_finish(acc, cacc, Ex, gp, bh, lane, l15, l4, arow, jq0, Hdec);
        group_arrive(flags, g, jt, tid, (unsigned)(t + 1));
    }

    // ---- folded decoder weights (Wcomb, K=512)
    const int kd0 = gp * 256;
    #pragma unroll
    for (int q = 0; q < 4; ++q)
        #pragma unroll
        for (int i = 0; i < 8; ++i)
            Breg[q * 8 + i] = *(const bf16x8*)(
                Wcomb + (size_t)(q * HID + jcol) * HID + kd0 + i * 32 + l4 * 8);
    #pragma unroll
    for (int n = 0; n < 32; ++n) asm volatile("" : "+v"(Breg[n]));

    // ================= decoder: t = 169..215 =================
    for (int t = TIN + 1; t < NSTEPS; ++t) {
        group_wait(flags, g, tid, (unsigned)t);
        const bf16_t* hprev = Hdec + (size_t)(t - 1 - TIN) * BATCH * HID
                                   + (size_t)arow * HID + l4 * 8;
        bf16x8 a[8];
        #pragma unroll
        for (int i = 0; i < 8; ++i)
            a[i] = ld_h8(hprev + kd0 + i * 32);
        f32x4 acc[4];
        #pragma unroll
        for (int q = 0; q < 4; ++q)
            acc[q] = (gp == 0) ? biasD4[q] : (f32x4){0.f, 0.f, 0.f, 0.f};
        #pragma unroll
        for (int i = 0; i < 8; ++i)
            #pragma unroll
            for (int q = 0; q < 4; ++q)
                acc[q] = __builtin_amdgcn_mfma_f32_16x16x32_bf16(Breg[q * 8 + i], a[i], acc[q], 0, 0, 0);
        cell_finish(acc, cacc, Ex, gp, bh, lane, l15, l4, arow, jq0,
                    Hdec + (size_t)(t - TIN) * BATCH * HID);
        group_arrive(flags, g, jt, tid, (unsigned)(t + 1));
    }
}

// ---------------------------------------------------------------------------
// Final projection: out[b,t,f] = sum_j Hdec[t][b][j] * Wlin[f][j]
__global__ __launch_bounds__(128)
void final_proj_kernel(const bf16_t* __restrict__ Hdec, const bf16_t* __restrict__ Wlin,
                       float* __restrict__ out) {
    int tid = threadIdx.x;
    int wv = tid >> 6, lane = tid & 63;
    int l15 = lane & 15, l4 = lane >> 4;
    int row0 = blockIdx.x * 32 + wv * 16;
    const bf16_t* arow = Hdec + (size_t)(row0 + l15) * HID;
    f32x4 acc[8];
    #pragma unroll
    for (int n = 0; n < 8; ++n) acc[n] = (f32x4){0.f, 0.f, 0.f, 0.f};
    #pragma unroll 4
    for (int kc = 0; kc < HID; kc += 32) {
        bf16x8 af = *(const bf16x8*)(arow + kc + l4 * 8);
        #pragma unroll
        for (int n = 0; n < 8; ++n) {
            bf16x8 bfr = *(const bf16x8*)(Wlin + (size_t)(n * 16 + l15) * HID + kc + l4 * 8);
            acc[n] = __builtin_amdgcn_mfma_f32_16x16x32_bf16(af, bfr, acc[n], 0, 0, 0);
        }
    }
    #pragma unroll
    for (int n = 0; n < 8; ++n) {
        int f = n * 16 + l15;
        #pragma unroll
        for (int r = 0; r < 4; ++r) {
            int row = row0 + l4 * 4 + r;
            int t = row >> 8;
            int b = row & 255;
            out[(size_t)b * (TOUT * FEAT) + (size_t)t * FEAT + f] = acc[n][r];
        }
    }
}

// ---------------------------------------------------------------------------
extern "C" void kernel_launch(void* const* d_in, const int* in_sizes, int n_in,
                              void* d_out, int out_size, void* d_ws, size_t ws_size,
                              hipStream_t stream) {
    const float* x       = (const float*)d_in[0];
    const float* enc_Wih = (const float*)d_in[1];
    const float* enc_Whh = (const float*)d_in[2];
    const float* enc_b   = (const float*)d_in[3];
    const float* dec_Wih = (const float*)d_in[4];
    const float* dec_Whh = (const float*)d_in[5];
    const float* dec_b   = (const float*)d_in[6];
    const float* W_lin   = (const float*)d_in[7];
    float* out = (float*)d_out;

    char* p = (char*)d_ws;
    auto alloc = [&](size_t bytes) -> void* {
        void* r = (void*)p;
        p += (bytes + 255) & ~(size_t)255;
        return r;
    };
    bf16_t* Xbf    = (bf16_t*)alloc((size_t)TIN * BATCH * FEAT * 2);   // 11 MB
    bf16_t* Wenc   = (bf16_t*)alloc((size_t)2048 * 640 * 2);           // 2.6 MB
    bf16_t* Wdec1  = (bf16_t*)alloc((size_t)2048 * 640 * 2);           // 2.6 MB
    bf16_t* Wcomb  = (bf16_t*)alloc((size_t)2048 * HID * 2);           // 2.1 MB
    bf16_t* Wlinb  = (bf16_t*)alloc((size_t)FEAT * HID * 2);           // 128 KB
    bf16_t* hbufA  = (bf16_t*)alloc((size_t)BATCH * HID * 2);          // 256 KB
    bf16_t* hbufB  = (bf16_t*)alloc((size_t)BATCH * HID * 2);          // 256 KB
    bf16_t* Hdec   = (bf16_t*)alloc((size_t)TOUT * BATCH * HID * 2);   // 12.6 MB
    u32* flags     = (u32*)alloc((size_t)NGRP * NJT * 4);              // 1 KB

    // per-launch state init (replay-safe)
    (void)hipMemsetAsync(hbufA, 0, (size_t)BATCH * HID * 2, stream);
    (void)hipMemsetAsync(flags, 0, (size_t)NGRP * NJT * 4, stream);

    // precompute
    cast_x_kernel<<<(BATCH * TIN * (FEAT / 4) + 255) / 256, 256, 0, stream>>>(x, Xbf);
    cast_wcat_kernel<<<(2048 * 160 + 255) / 256, 256, 0, stream>>>(enc_Wih, enc_Whh, Wenc);
    cast_wcat_kernel<<<(2048 * 160 + 255) / 256, 256, 0, stream>>>(dec_Wih, dec_Whh, Wdec1);
    cast_wlin_kernel<<<(FEAT * HID / 4 + 255) / 256, 256, 0, stream>>>(W_lin, Wlinb);
    build_wcomb_kernel<<<dim3(2048 / 64, HID / 64), 256, 0, stream>>>(dec_Wih, dec_Whh, W_lin, Wcomb);

    // all 216 recurrent steps in one persistent kernel
    lstm_persist<<<NGRP * NJT, 256, 0, stream>>>(Xbf, Wenc, enc_b, Wdec1, Wcomb, dec_b,
                                                 hbufA, hbufB, Hdec, flags);

    // batched output projection (48 x 256 rows @ W_lin^T)
    final_proj_kernel<<<(TOUT * BATCH) / 32, 128, 0, stream>>>(Hdec, Wlinb, out);
}